// Round 11
// baseline (113.855 us; speedup 1.0000x reference)
//
#include <hip/hip_runtime.h>

#define NPTS 262144
#define HP1 2654435761u
#define HP2 805459861u
#define TMASK 0x7FFFFu

typedef __attribute__((ext_vector_type(8))) short short8;
typedef __attribute__((ext_vector_type(4))) float f32x4;
typedef unsigned short ushort_t;
typedef unsigned int uint_t;

#define MFMA(a, b, c) __builtin_amdgcn_mfma_f32_16x16x32_bf16((a), (b), (c), 0, 0, 0)

__device__ __forceinline__ ushort_t f2bf(float f) {
    uint_t u = __float_as_uint(f);
    return (ushort_t)((u + 0x7FFFu + ((u >> 16) & 1u)) >> 16);
}
__device__ __forceinline__ float sigmoidf_fast(float v) {
    return 1.0f / (1.0f + __expf(-v));
}

// ws layout: [0,16MB) feats ([L][N] packed bf16 pair), [16MB,+24KB) weight frags
#define WS_WF_OFF (16u * 1024u * 1024u)

// Weight-fragment offsets (ushort elements)
#define OFF_DW1 0
#define OFF_DW2 2048
#define OFF_CW1 3072
#define OFF_CW2 7168
#define OFF_CW3 11264
#define WF_TOTAL 12288

#define ENC_BLOCKS 16384   // 16 levels x 1024
#define PREP_BLOCKS 48

// ---------------- Dispatch 1: hash-grid encode + weight prep (merged) ----------------
extern "C" __global__ void __launch_bounds__(256) ngp_encode(
    const float* __restrict__ xin, const float* __restrict__ tbl,
    uint_t* __restrict__ feats,
    const float* __restrict__ dW1, const float* __restrict__ dW2,
    const float* __restrict__ cW1, const float* __restrict__ cW2,
    const float* __restrict__ cW3, ushort_t* __restrict__ wf)
{
    const int b = blockIdx.x;
    if (b >= ENC_BLOCKS) {
        // ---- weight-fragment pack (48 blocks) ----
        const int e = (b - ENC_BLOCKS) * 256 + (int)threadIdx.x;
        if (e >= WF_TOTAL) return;
        const float* W; int base, NT, KR, NR;
        if (e < OFF_DW2)      { W = dW1; base = OFF_DW1; NT = 4; KR = 32; NR = 64; }
        else if (e < OFF_CW1) { W = dW2; base = OFF_DW2; NT = 1; KR = 64; NR = 16; }
        else if (e < OFF_CW2) { W = cW1; base = OFF_CW1; NT = 4; KR = 43; NR = 64; }
        else if (e < OFF_CW3) { W = cW2; base = OFF_CW2; NT = 4; KR = 64; NR = 64; }
        else                  { W = cW3; base = OFF_CW3; NT = 1; KR = 64; NR = 3;  }
        const int r = e - base;
        const int frag = r >> 9;
        const int lane = (r >> 3) & 63;
        const int j = r & 7;
        const int kc = frag / NT, nt = frag % NT;
        const int k = kc * 32 + ((lane >> 4) << 3) + j;
        const int n = nt * 16 + (lane & 15);
        const float v = (k < KR && n < NR) ? W[k * NR + n] : 0.0f;
        wf[e] = f2bf(v);
        return;
    }

    const int l  = b >> 10;
    const int pt = ((b & 1023) << 8) + (int)threadIdx.x;

    static const float NLs[16] = {16.f, 22.f, 30.f, 42.f, 58.f, 80.f, 111.f, 153.f,
                                  212.f, 294.f, 406.f, 561.f, 776.f, 1072.f, 1482.f, 2048.f};

    const float x0 = xin[3 * pt + 0];
    const float x1 = xin[3 * pt + 1];
    const float x2 = xin[3 * pt + 2];
    const bool msk = (fabsf(x0) < 1.5f) & (fabsf(x1) < 1.5f) & (fabsf(x2) < 1.5f);
    if (!msk) return;

    const float nl = NLs[l];
    const float s0 = (x0 / 3.0f + 0.5f) * nl;
    const float s1 = (x1 / 3.0f + 0.5f) * nl;
    const float s2 = (x2 / 3.0f + 0.5f) * nl;
    const float f0 = floorf(s0), f1 = floorf(s1), f2 = floorf(s2);
    const float l0 = s0 - f0, l1 = s1 - f1, l2 = s2 - f2;
    const float m0 = 1.0f - l0, m1 = 1.0f - l1, m2 = 1.0f - l2;

    const float2* tp = (const float2*)tbl + ((size_t)l << 19);
    const unsigned va0 = (unsigned)(int)f0, vb0 = va0 + 1u;
    const unsigned va1 = (unsigned)(int)f1 * HP1, vb1 = va1 + HP1;
    const unsigned va2 = (unsigned)(int)f2 * HP2, vb2 = va2 + HP2;
    const float2 c0 = tp[(va0 ^ va1 ^ va2) & TMASK];
    const float2 c1 = tp[(vb0 ^ va1 ^ va2) & TMASK];
    const float2 c2 = tp[(va0 ^ vb1 ^ va2) & TMASK];
    const float2 c3 = tp[(vb0 ^ vb1 ^ va2) & TMASK];
    const float2 c4 = tp[(va0 ^ va1 ^ vb2) & TMASK];
    const float2 c5 = tp[(vb0 ^ va1 ^ vb2) & TMASK];
    const float2 c6 = tp[(va0 ^ vb1 ^ vb2) & TMASK];
    const float2 c7 = tp[(vb0 ^ vb1 ^ vb2) & TMASK];

    float a = 0.0f, bb = 0.0f, w;
    w = m1 * m2; a = fmaf(m0 * w, c0.x, a); bb = fmaf(m0 * w, c0.y, bb);
                 a = fmaf(l0 * w, c1.x, a); bb = fmaf(l0 * w, c1.y, bb);
    w = l1 * m2; a = fmaf(m0 * w, c2.x, a); bb = fmaf(m0 * w, c2.y, bb);
                 a = fmaf(l0 * w, c3.x, a); bb = fmaf(l0 * w, c3.y, bb);
    w = m1 * l2; a = fmaf(m0 * w, c4.x, a); bb = fmaf(m0 * w, c4.y, bb);
                 a = fmaf(l0 * w, c5.x, a); bb = fmaf(l0 * w, c5.y, bb);
    w = l1 * l2; a = fmaf(m0 * w, c6.x, a); bb = fmaf(m0 * w, c6.y, bb);
                 a = fmaf(l0 * w, c7.x, a); bb = fmaf(l0 * w, c7.y, bb);

    feats[(size_t)l * NPTS + pt] = (uint_t)f2bf(a) | ((uint_t)f2bf(bb) << 16);
}

// ---------------- Dispatch 2: MFMA MLPs — one wave per 16 points (M=16) ----------------
// Smaller acc tile (acc[4] instead of acc[4][4]) -> ~64-80 VGPR -> 6-8 waves/SIMD.
// 16384 blocks x 64 threads. LDS act tile [16 rows][64 cols] bf16, XOR-swizzled.
extern "C" __global__ void __launch_bounds__(64) ngp_mlp(
    const float* __restrict__ xin, const float* __restrict__ din,
    const uint_t* __restrict__ featsbf, const ushort_t* __restrict__ wf,
    const float* __restrict__ db1, const float* __restrict__ db2,
    const float* __restrict__ cb1, const float* __restrict__ cb2,
    const float* __restrict__ cb3,
    float* __restrict__ out)
{
    __shared__ short act[1024];      // [16][64] bf16
    __shared__ float mk[16];

    const int lane = (int)threadIdx.x;
    const int lrow = lane & 15;      // row (point) for A-frags / col for D-frags
    const int lq   = lane >> 4;      // k-group / row-group
    const int ptb  = blockIdx.x * 16;
    char* Ab = (char*)&act[0];

#define LDSA(kc) (*reinterpret_cast<const short8*>(Ab + ((lrow * 128 + (kc) * 64 + lq * 16) ^ ((lrow & 7) << 4))))
#define LOADB(off)   (*reinterpret_cast<const short8*>(wf + (off) + lane * 8))
#define STB16(row, col, val) *reinterpret_cast<ushort_t*>(Ab + ((((row) * 128 + (col) * 2)) ^ (((row) & 7) << 4))) = (val)

    // mask: lanes 0..15 own one point each
    if (lane < 16) {
        const float x0 = xin[3 * (ptb + lane) + 0];
        const float x1 = xin[3 * (ptb + lane) + 1];
        const float x2 = xin[3 * (ptb + lane) + 2];
        const bool msk = (fabsf(x0) < 1.5f) & (fabsf(x1) < 1.5f) & (fabsf(x2) < 1.5f);
        mk[lane] = msk ? 1.0f : 0.0f;
    }

    // feats -> LDS: lane (row=lrow, g=lq) loads levels 4g..4g+3 of point ptb+lrow
    {
        uint_t u[4];
        #pragma unroll
        for (int i = 0; i < 4; ++i)
            u[i] = featsbf[(size_t)(4 * lq + i) * NPTS + ptb + lrow];
        short8 v;
        #pragma unroll
        for (int i = 0; i < 4; ++i) {
            v[2 * i + 0] = (short)(u[i] & 0xFFFFu);
            v[2 * i + 1] = (short)(u[i] >> 16);
        }
        const int byte = (lrow * 128 + 16 * lq) ^ ((lrow & 7) << 4);
        *reinterpret_cast<short8*>(Ab + byte) = v;
    }
    // this lane's d for PE (row = lrow's point) — each lane loads its own row's d
    const float d0v = din[3 * (ptb + lrow) + 0];
    const float d1v = din[3 * (ptb + lrow) + 1];
    const float d2v = din[3 * (ptb + lrow) + 2];

    __syncthreads();

    // ---- Layer D1: feats[16x32] @ dW1[32x64] ----
    f32x4 acc[4];
    #pragma unroll
    for (int nt = 0; nt < 4; ++nt) {
        const float b = db1[nt * 16 + lrow];
        acc[nt] = (f32x4){b, b, b, b};
    }
    {
        const short8 a0 = LDSA(0);
        #pragma unroll
        for (int nt = 0; nt < 4; ++nt)
            acc[nt] = MFMA(a0, LOADB(OFF_DW1 + nt * 512), acc[nt]);
    }
    __syncthreads();
    #pragma unroll
    for (int nt = 0; nt < 4; ++nt)
        #pragma unroll
        for (int r = 0; r < 4; ++r)
            STB16(lq * 4 + r, nt * 16 + lrow, f2bf(fmaxf(acc[nt][r], 0.0f)));
    __syncthreads();

    // ---- Layer D2: hid[16x64] @ dW2[64x16] ----
    f32x4 hD;
    {
        const float b = db2[lrow];
        hD = (f32x4){b, b, b, b};
        #pragma unroll
        for (int kc = 0; kc < 2; ++kc)
            hD = MFMA(LDSA(kc), LOADB(OFF_DW2 + kc * 512), hD);
    }
    __syncthreads();

    // sigma (col 0 of h): lanes with lrow==0 hold rows 4*lq+r
    if (lrow == 0) {
        #pragma unroll
        for (int r = 0; r < 4; ++r) {
            const int row = lq * 4 + r;
            out[3 * NPTS + ptb + row] = (mk[row] != 0.0f) ? __expf(hD[r]) : 0.0f;
        }
    }
    // h -> ch cols 0..15 (raw)
    #pragma unroll
    for (int r = 0; r < 4; ++r)
        STB16(lq * 4 + r, lrow, f2bf(hD[r]));
    // d_enc -> ch cols 16..63: lane (row=lrow, g=lq) fills cols [16+12g, 28+12g)
    {
        const float dv[3] = {d0v, d1v, d2v};
        #pragma unroll
        for (int i = 0; i < 12; ++i) {
            const int e = 12 * lq + i;      // 0..47 over the 48 cols 16..63
            float val = 0.0f;
            if (e < 3) val = dv[e];
            else if (e < 27) {
                const int j = (e - 3) / 6, cc = (e - 3) % 6;
                const float s = (float)(1 << j);
                val = (cc < 3) ? __sinf(s * dv[cc]) : __cosf(s * dv[cc - 3]);
            }
            STB16(lrow, 16 + e, f2bf(val));
        }
    }
    __syncthreads();

    // ---- Layer C1: ch[16x64(43)] @ cW1[64x64] ----
    #pragma unroll
    for (int nt = 0; nt < 4; ++nt) {
        const float b = cb1[nt * 16 + lrow];
        acc[nt] = (f32x4){b, b, b, b};
    }
    #pragma unroll
    for (int kc = 0; kc < 2; ++kc) {
        const short8 a0 = LDSA(kc);
        #pragma unroll
        for (int nt = 0; nt < 4; ++nt)
            acc[nt] = MFMA(a0, LOADB(OFF_CW1 + (kc * 4 + nt) * 512), acc[nt]);
    }
    __syncthreads();
    #pragma unroll
    for (int nt = 0; nt < 4; ++nt)
        #pragma unroll
        for (int r = 0; r < 4; ++r)
            STB16(lq * 4 + r, nt * 16 + lrow, f2bf(fmaxf(acc[nt][r], 0.0f)));
    __syncthreads();

    // ---- Layer C2: c1[16x64] @ cW2[64x64] ----
    #pragma unroll
    for (int nt = 0; nt < 4; ++nt) {
        const float b = cb2[nt * 16 + lrow];
        acc[nt] = (f32x4){b, b, b, b};
    }
    #pragma unroll
    for (int kc = 0; kc < 2; ++kc) {
        const short8 a0 = LDSA(kc);
        #pragma unroll
        for (int nt = 0; nt < 4; ++nt)
            acc[nt] = MFMA(a0, LOADB(OFF_CW2 + (kc * 4 + nt) * 512), acc[nt]);
    }
    __syncthreads();
    #pragma unroll
    for (int nt = 0; nt < 4; ++nt)
        #pragma unroll
        for (int r = 0; r < 4; ++r)
            STB16(lq * 4 + r, nt * 16 + lrow, f2bf(fmaxf(acc[nt][r], 0.0f)));
    __syncthreads();

    // ---- Layer C3: c2[16x64] @ cW3[64x3(pad16)] ----
    f32x4 rD;
    {
        const float b = (lrow < 3) ? cb3[lrow] : 0.0f;
        rD = (f32x4){b, b, b, b};
        #pragma unroll
        for (int kc = 0; kc < 2; ++kc)
            rD = MFMA(LDSA(kc), LOADB(OFF_CW3 + kc * 512), rD);
    }
    if (lrow < 3) {
        #pragma unroll
        for (int r = 0; r < 4; ++r) {
            const int row = lq * 4 + r;
            out[3 * (ptb + row) + lrow] = (mk[row] != 0.0f) ? sigmoidf_fast(rD[r]) : 0.0f;
        }
    }
#undef LDSA
#undef LOADB
#undef STB16
}

extern "C" void kernel_launch(void* const* d_in, const int* in_sizes, int n_in,
                              void* d_out, int out_size, void* d_ws, size_t ws_size,
                              hipStream_t stream) {
    const float* x    = (const float*)d_in[0];
    const float* d    = (const float*)d_in[1];
    const float* tbl  = (const float*)d_in[2];
    const float* dW1  = (const float*)d_in[3];
    const float* db1  = (const float*)d_in[4];
    const float* dW2  = (const float*)d_in[5];
    const float* db2  = (const float*)d_in[6];
    const float* cW1  = (const float*)d_in[7];
    const float* cb1  = (const float*)d_in[8];
    const float* cW2  = (const float*)d_in[9];
    const float* cb2  = (const float*)d_in[10];
    const float* cW3  = (const float*)d_in[11];
    const float* cb3  = (const float*)d_in[12];

    uint_t* feats = (uint_t*)d_ws;                               // 16 MB
    ushort_t* wfr = (ushort_t*)((char*)d_ws + WS_WF_OFF);        // 24 KB

    ngp_encode<<<ENC_BLOCKS + PREP_BLOCKS, 256, 0, stream>>>(
        x, tbl, feats, dW1, dW2, cW1, cW2, cW3, wfr);
    ngp_mlp<<<NPTS / 16, 64, 0, stream>>>(
        x, d, feats, wfr, db1, db2, cb1, cb2, cb3, (float*)d_out);
}